// Round 1
// 749.365 us; speedup vs baseline: 1.1031x; 1.1031x over previous
//
#include <hip/hip_runtime.h>
#include <stdint.h>

typedef unsigned short u16;
typedef __bf16 bf16x8 __attribute__((ext_vector_type(8)));
typedef float  f32x4  __attribute__((ext_vector_type(4)));

#define GLOBAL_AS __attribute__((address_space(1)))
#define LDS_AS    __attribute__((address_space(3)))

#define B_ 4
#define L_ 4096
#define D_ 1024
#define H_ 16
#define TD 3072         // 3*D
#define NCHUNK 16
#define TCHUNK 256      // L_/NCHUNK

__device__ __forceinline__ float bf2f(u16 h) {
    union { uint32_t u; float f; } v; v.u = ((uint32_t)h) << 16; return v.f;
}
__device__ __forceinline__ u16 f2bf(float f) {
    union { float f; uint32_t u; } v; v.f = f;
    uint32_t u = v.u;
    u += 0x7fffu + ((u >> 16) & 1u);   // round-to-nearest-even
    return (u16)(u >> 16);
}
__device__ __forceinline__ void unp8(uint4 u, float* f) {
    f[0] = bf2f((u16)(u.x)); f[1] = bf2f((u16)(u.x >> 16));
    f[2] = bf2f((u16)(u.y)); f[3] = bf2f((u16)(u.y >> 16));
    f[4] = bf2f((u16)(u.z)); f[5] = bf2f((u16)(u.z >> 16));
    f[6] = bf2f((u16)(u.w)); f[7] = bf2f((u16)(u.w >> 16));
}

// pack 8 contiguous fp32 into 8 bf16 (RTE) -- identical rounding to prior version
__device__ __forceinline__ uint4 ld8f(const float* p) {
    const float4 a = *(const float4*)p;
    const float4 b = *(const float4*)(p + 4);
    uint4 r;
    r.x = (uint32_t)f2bf(a.x) | ((uint32_t)f2bf(a.y) << 16);
    r.y = (uint32_t)f2bf(a.z) | ((uint32_t)f2bf(a.w) << 16);
    r.z = (uint32_t)f2bf(b.x) | ((uint32_t)f2bf(b.y) << 16);
    r.w = (uint32_t)f2bf(b.z) | ((uint32_t)f2bf(b.w) << 16);
    return r;
}

// store helper: C is bf16 (qkv intermediate) or fp32 (final output)
__device__ __forceinline__ void stc(u16* p, float v)   { *p = f2bf(v); }
__device__ __forceinline__ void stc(float* p, float v) { *p = v; }

// fp32 -> bf16 bulk convert, 8 elems/thread
__global__ __launch_bounds__(256) void cvt_f32_bf16(
    const float* __restrict__ in, u16* __restrict__ out, size_t n8)
{
    size_t i = (size_t)blockIdx.x * 256 + threadIdx.x;
    if (i >= n8) return;
    *(uint4*)(out + i * 8) = ld8f(in + i * 8);
}

// ---------------------------------------------------------------------------
// NT GEMM (m97 structure): C(M,N) = A(M,K)bf16 @ W(N,K)bf16^T + bias(fp32).
// 128x128 tile, BK=32, 256 thr (4 waves), 4x4 16x16x32 MFMA per wave.
// Staging via global_load_lds width=16 into LINEAR LDS [128][32] (no pad --
// global_load_lds dest is wave-uniform base + lane*16; layout must be linear).
// Fragment mapping identical to prior verified kernel (only pitch changed).
// ---------------------------------------------------------------------------
template <typename TC>
__global__ __launch_bounds__(256) void gemm_bt_bias_bf16(
    const u16* __restrict__ A, const u16* __restrict__ W,
    const float* __restrict__ bias, TC* __restrict__ C,
    int M, int N, int K)
{
    __shared__ u16 As[128 * 32];
    __shared__ u16 Bs[128 * 32];

    const int tid  = threadIdx.x;
    const int lane = tid & 63;
    const int wid  = tid >> 6;
    const int bm = blockIdx.y * 128;
    const int bn = blockIdx.x * 128;

    const int wm = (wid & 1) * 64;
    const int wn = (wid >> 1) * 64;
    const int fr   = lane & 15;
    const int quad = lane >> 4;

    // staging: thread t covers rows (t>>2) and (t>>2)+64, k-group (t&3)*8.
    // LDS dest for lane l of wave w (round p): ((p*256 + w*64 + l) * 8) u16
    //   = row (p*64 + t>>2) * 32 + (t&3)*8  -- row-major [128][32], consistent.
    const u16* Ag = A + (size_t)(bm + (tid >> 2)) * K + (tid & 3) * 8;
    const u16* Wg = W + (size_t)(bn + (tid >> 2)) * K + (tid & 3) * 8;
    const size_t rskip = (size_t)64 * K;

    u16* AsW = As + wid * 512;      // wave-uniform LDS base, round 0
    u16* BsW = Bs + wid * 512;

    f32x4 acc[4][4] = {};

    for (int k0 = 0; k0 < K; k0 += 32) {
        __syncthreads();            // all waves done reading previous tile
        __builtin_amdgcn_global_load_lds((const GLOBAL_AS void*)(Ag + k0),
                                         (LDS_AS void*)(AsW),        16, 0, 0);
        __builtin_amdgcn_global_load_lds((const GLOBAL_AS void*)(Ag + rskip + k0),
                                         (LDS_AS void*)(AsW + 2048), 16, 0, 0);
        __builtin_amdgcn_global_load_lds((const GLOBAL_AS void*)(Wg + k0),
                                         (LDS_AS void*)(BsW),        16, 0, 0);
        __builtin_amdgcn_global_load_lds((const GLOBAL_AS void*)(Wg + rskip + k0),
                                         (LDS_AS void*)(BsW + 2048), 16, 0, 0);
        __syncthreads();            // compiler drains vmcnt(0) before barrier

        bf16x8 af[4], bfv[4];
#pragma unroll
        for (int tm = 0; tm < 4; ++tm) {
            int m = wm + tm * 16 + fr;
            af[tm] = *(const bf16x8*)&As[m * 32 + quad * 8];
        }
#pragma unroll
        for (int tn = 0; tn < 4; ++tn) {
            int n = wn + tn * 16 + fr;
            bfv[tn] = *(const bf16x8*)&Bs[n * 32 + quad * 8];
        }
#pragma unroll
        for (int tm = 0; tm < 4; ++tm)
#pragma unroll
            for (int tn = 0; tn < 4; ++tn)
                acc[tm][tn] = __builtin_amdgcn_mfma_f32_16x16x32_bf16(
                    af[tm], bfv[tn], acc[tm][tn], 0, 0, 0);
    }

    // epilogue: C/D layout col=lane&15, row=quad*4+reg (m89/m91-verified)
#pragma unroll
    for (int tm = 0; tm < 4; ++tm) {
#pragma unroll
        for (int tn = 0; tn < 4; ++tn) {
            const int col = bn + wn + tn * 16 + fr;
            const float bv = bias[col];
#pragma unroll
            for (int r = 0; r < 4; ++r) {
                const int row = bm + wm + tm * 16 + quad * 4 + r;
                stc(&C[(size_t)row * N + col], acc[tm][tn][r] + bv);
            }
        }
    }
}

// ---------------------------------------------------------------------------
// STP scan, chunked linear recurrence (on-device verified == naive scan).
// state[i][j] <- R*state + (Gam/8)*v_i*k_j; y_i = sum_j (W+S)_ij q_j.
// Thread (i=t/4, jc=t&3) owns state row i, cols jc*16..+16 in fp32 regs.
// ---------------------------------------------------------------------------
__global__ __launch_bounds__(256) void stp_scan_local(
    const u16* __restrict__ qkv, const float* __restrict__ Lam,
    const float* __restrict__ Gam, float* __restrict__ F)
{
    const int c = blockIdx.x, h = blockIdx.y, b = blockIdx.z;
    const int t = threadIdx.x;
    const int i = t >> 2, jc = t & 3, j0 = jc << 4;
    const int hij = (h << 12) + (i << 6) + j0;

    float R[16], Gv[16], s[16];
#pragma unroll
    for (int j = 0; j < 16; ++j) {
        R[j]  = 1.0f / (1.0f + expf(Lam[hij + j]));  // 1-sigmoid(x)=sigmoid(-x)
        Gv[j] = Gam[hij + j] * 0.125f;               // fold k scale 1/sqrt(64)
        s[j]  = 0.0f;
    }

    const u16* rowp = qkv + (size_t)(b * L_ + c * TCHUNK) * TD;
    const int koff = D_ + (h << 6) + j0;
    const int voff = 2 * D_ + (h << 6) + i;

    for (int tt = 0; tt < TCHUNK; ++tt, rowp += TD) {
        const float v = bf2f(rowp[voff]);
        uint4 ku0 = *(const uint4*)(rowp + koff);
        uint4 ku1 = *(const uint4*)(rowp + koff + 8);
        float kf[16];
        unp8(ku0, kf); unp8(ku1, kf + 8);
#pragma unroll
        for (int j = 0; j < 16; ++j)
            s[j] = fmaf(R[j], s[j], (Gv[j] * v) * kf[j]);
    }

    float* Fp = F + (((size_t)(b * H_ + h) * NCHUNK + c) << 12) + (i << 6) + j0;
#pragma unroll
    for (int j = 0; j < 16; j += 4)
        *(f32x4*)(Fp + j) = *(const f32x4*)(s + j);
}

// Sequential chunk combine per (b,h), in place: F[c] becomes Sinit[c]
// (state BEFORE chunk c). Sinit[c] = Rt ⊙ Sinit[c-1] + F[c-1], Rt = R^TCHUNK.
__global__ __launch_bounds__(256) void stp_combine(
    const float* __restrict__ Lam, float* __restrict__ F)
{
    const int h = blockIdx.x, b = blockIdx.y;
    const int t = threadIdx.x;
    const int i = t >> 2, jc = t & 3, j0 = jc << 4;
    const int hij = (h << 12) + (i << 6) + j0;

    float Rt[16], s[16];
#pragma unroll
    for (int j = 0; j < 16; ++j) {
        float R = 1.0f / (1.0f + expf(Lam[hij + j]));
        Rt[j] = powf(R, (float)TCHUNK);
        s[j] = 0.0f;
    }
    float* base = F + (((size_t)(b * H_ + h) * NCHUNK) << 12) + (i << 6) + j0;
    for (int c = 0; c < NCHUNK; ++c) {
        float* p = base + ((size_t)c << 12);
        float tmp[16];
#pragma unroll
        for (int j = 0; j < 16; ++j) tmp[j] = p[j];
#pragma unroll
        for (int j = 0; j < 16; ++j) { p[j] = s[j]; s[j] = fmaf(Rt[j], s[j], tmp[j]); }
    }
}

__global__ __launch_bounds__(256) void stp_scan_out(
    const u16* __restrict__ qkv, const float* __restrict__ Lam,
    const float* __restrict__ Gam, const float* __restrict__ Wst,
    const float* __restrict__ Sinit, u16* __restrict__ y)
{
    const int c = blockIdx.x, h = blockIdx.y, b = blockIdx.z;
    const int t = threadIdx.x;
    const int i = t >> 2, jc = t & 3, j0 = jc << 4;
    const int hij = (h << 12) + (i << 6) + j0;

    float R[16], Gv[16], Wr[16], s[16];
    const float* Sp = Sinit + (((size_t)(b * H_ + h) * NCHUNK + c) << 12) + (i << 6) + j0;
#pragma unroll
    for (int j = 0; j < 16; ++j) {
        R[j]  = 1.0f / (1.0f + expf(Lam[hij + j]));
        Gv[j] = Gam[hij + j] * 0.125f;
        Wr[j] = Wst[hij + j];
        s[j]  = Sp[j];
    }

    const u16* rowp = qkv + (size_t)(b * L_ + c * TCHUNK) * TD;
    const int qoff = (h << 6) + j0;
    const int koff = D_ + qoff;
    const int voff = 2 * D_ + (h << 6) + i;
    u16* yp = y + (size_t)(b * L_ + c * TCHUNK) * D_ + (h << 6) + i;

    for (int tt = 0; tt < TCHUNK; ++tt, rowp += TD, yp += D_) {
        const float v = bf2f(rowp[voff]);
        uint4 qu0 = *(const uint4*)(rowp + qoff);
        uint4 qu1 = *(const uint4*)(rowp + qoff + 8);
        uint4 ku0 = *(const uint4*)(rowp + koff);
        uint4 ku1 = *(const uint4*)(rowp + koff + 8);
        float kf[16], qf[16];
        unp8(ku0, kf); unp8(ku1, kf + 8);
        unp8(qu0, qf); unp8(qu1, qf + 8);

        float ya = 0.0f, yb = 0.0f;
#pragma unroll
        for (int j = 0; j < 16; j += 2) {
            s[j]     = fmaf(R[j],     s[j],     (Gv[j]     * v) * kf[j]);
            s[j + 1] = fmaf(R[j + 1], s[j + 1], (Gv[j + 1] * v) * kf[j + 1]);
            ya = fmaf(Wr[j]     + s[j],     qf[j],     ya);
            yb = fmaf(Wr[j + 1] + s[j + 1], qf[j + 1], yb);
        }
        float yacc = ya + yb;
        yacc += __shfl_xor(yacc, 1, 64);
        yacc += __shfl_xor(yacc, 2, 64);
        if (jc == 0) *yp = f2bf(yacc);
    }
}

__global__ void zero_out_f32(float* p, size_t n) {
    size_t i = (size_t)blockIdx.x * blockDim.x + threadIdx.x;
    if (i < n) p[i] = 0.0f;
}

// ---------------------------------------------------------------------------
extern "C" void kernel_launch(void* const* d_in, const int* in_sizes, int n_in,
                              void* d_out, int out_size, void* d_ws, size_t ws_size,
                              hipStream_t stream)
{
    const float* x      = (const float*)d_in[0];
    const float* Wqkv_w = (const float*)d_in[1];
    const float* Wqkv_b = (const float*)d_in[2];
    const float* out_w  = (const float*)d_in[3];
    const float* out_b  = (const float*)d_in[4];
    const float* Wst    = (const float*)d_in[5];
    const float* Lam    = (const float*)d_in[6];
    const float* Gam    = (const float*)d_in[7];
    float* out = (float*)d_out;                    // fp32 output (r7 probe-proven)

    // ws carve (151.0 MB, unchanged): qkv bf16 | y bf16 | F fp32.
    // Aliases (stream-order proven dead/live):
    //   xb (x as bf16, 33.5MB)   -> y region   (y written later by stp_scan_out)
    //   wqkvb (6.3MB)            -> F region   (F written later by stp_scan_local)
    //   outwb (2.1MB)            -> F region   (converted AFTER stp_scan_out)
    const size_t need = (size_t)B_ * L_ * TD * 2 + (size_t)B_ * L_ * D_ * 2
                      + (size_t)B_ * H_ * NCHUNK * 64 * 64 * 4;
    if (ws_size < need) {
        zero_out_f32<<<(out_size + 255) / 256, 256, 0, stream>>>(out, (size_t)out_size);
        return;
    }
    u16*   qkv = (u16*)d_ws;                                  // 50331648 elems
    u16*   y   = qkv + (size_t)B_ * L_ * TD;                  // 16777216 elems
    float* F   = (float*)(y + (size_t)B_ * L_ * D_);          //  4194304 floats
    u16*   xb    = y;                                         // alias, see above
    u16*   wqkvb = (u16*)F;                                   // alias
    u16*   outwb = (u16*)F;                                   // alias

    cvt_f32_bf16<<<(B_ * L_ * D_ / 8 + 255) / 256, 256, 0, stream>>>(
        x, xb, (size_t)B_ * L_ * D_ / 8);
    cvt_f32_bf16<<<(TD * D_ / 8 + 255) / 256, 256, 0, stream>>>(
        Wqkv_w, wqkvb, (size_t)TD * D_ / 8);
    gemm_bt_bias_bf16<u16><<<dim3(TD / 128, (B_ * L_) / 128), 256, 0, stream>>>(
        xb, wqkvb, Wqkv_b, qkv, B_ * L_, TD, D_);
    stp_scan_local<<<dim3(NCHUNK, H_, B_), 256, 0, stream>>>(qkv, Lam, Gam, F);
    stp_combine<<<dim3(H_, B_), 256, 0, stream>>>(Lam, F);
    stp_scan_out<<<dim3(NCHUNK, H_, B_), 256, 0, stream>>>(qkv, Lam, Gam, Wst, F, y);
    cvt_f32_bf16<<<(D_ * D_ / 8 + 255) / 256, 256, 0, stream>>>(
        out_w, outwb, (size_t)D_ * D_ / 8);
    gemm_bt_bias_bf16<float><<<dim3(D_ / 128, (B_ * L_) / 128), 256, 0, stream>>>(
        y, outwb, out_b, out, B_ * L_, D_, D_);
}